// Round 1
// baseline (102.701 us; speedup 1.0000x reference)
//
#include <hip/hip_runtime.h>
#include <hip/hip_bf16.h>

// SpecAugment: out = (x + noise*0.04) masked by per-sample freq/time zero masks.
// x, noise: [B=128, C=3, F=128, T=1000] f32. f0/f_len: [B,2], t0/t_len: [B,2] i32.
// Memory-bound: ~590 MB ideal traffic. One block per (b,c,f) row, float4 loads.

#define B 128
#define C 3
#define Fd 128
#define T 1000
#define NOISE_STD 0.04f

__global__ __launch_bounds__(256) void specaug_kernel(
    const float* __restrict__ x, const float* __restrict__ noise,
    const int* __restrict__ f0, const int* __restrict__ f_len,
    const int* __restrict__ t0, const int* __restrict__ t_len,
    float* __restrict__ out)
{
    const int row = blockIdx.x;              // [0, B*C*Fd)
    const int f   = row % Fd;
    const int b   = row / (C * Fd);
    const int tid = threadIdx.x;             // 0..255; 250 active (250*4 = 1000)

    // Freq mask — uniform across the block (scalar path).
    const int fa0 = f0[b * 2 + 0], fl0 = f_len[b * 2 + 0];
    const int fa1 = f0[b * 2 + 1], fl1 = f_len[b * 2 + 1];
    const bool fmask = (f >= fa0 && f < fa0 + fl0) || (f >= fa1 && f < fa1 + fl1);

    const long long base = (long long)row * T;

    if (tid >= 250) return;

    float4* outp = reinterpret_cast<float4*>(out + base) + tid;

    if (fmask) {
        // Whole row zeroed — skip input reads entirely.
        float4 z; z.x = 0.f; z.y = 0.f; z.z = 0.f; z.w = 0.f;
        *outp = z;
        return;
    }

    const int ta0 = t0[b * 2 + 0], tl0 = t_len[b * 2 + 0];
    const int ta1 = t0[b * 2 + 1], tl1 = t_len[b * 2 + 1];

    const float4 xv = *(reinterpret_cast<const float4*>(x + base) + tid);
    const float4 nv = *(reinterpret_cast<const float4*>(noise + base) + tid);

    const int t = tid * 4;
    float r[4];
    const float xs[4] = {xv.x, xv.y, xv.z, xv.w};
    const float ns[4] = {nv.x, nv.y, nv.z, nv.w};
#pragma unroll
    for (int k = 0; k < 4; ++k) {
        const int tt = t + k;
        const bool tmask = (tt >= ta0 && tt < ta0 + tl0) || (tt >= ta1 && tt < ta1 + tl1);
        r[k] = tmask ? 0.f : fmaf(ns[k], NOISE_STD, xs[k]);
    }
    float4 ov; ov.x = r[0]; ov.y = r[1]; ov.z = r[2]; ov.w = r[3];
    *outp = ov;
}

extern "C" void kernel_launch(void* const* d_in, const int* in_sizes, int n_in,
                              void* d_out, int out_size, void* d_ws, size_t ws_size,
                              hipStream_t stream)
{
    const float* x     = (const float*)d_in[0];
    const float* noise = (const float*)d_in[1];
    const int*   f0    = (const int*)d_in[2];
    const int*   f_len = (const int*)d_in[3];
    const int*   t0    = (const int*)d_in[4];
    const int*   t_len = (const int*)d_in[5];
    float* out = (float*)d_out;

    const int nrows = B * C * Fd;   // 49152 blocks
    specaug_kernel<<<nrows, 256, 0, stream>>>(x, noise, f0, f_len, t0, t_len, out);
}